// Round 1
// baseline (923.349 us; speedup 1.0000x reference)
//
#include <hip/hip_runtime.h>
#include <hip/hip_bf16.h>

#define TLEN 4096
#define EDIM 2048
#define DDIM 128
#define BSZ  8
#define NT   32            // TLEN/128
#define MROWS (BSZ*TLEN)   // 32768

typedef unsigned short u16;
typedef __attribute__((ext_vector_type(8))) short bf16x8;  // 8 bf16 in 4 VGPRs
typedef __attribute__((ext_vector_type(4))) float f32x4;

// exp(scale * s) = exp2(C1 * s), scale = 1/sqrt(128)
#define C1F (0.08838834764831845f * 1.4426950408889634f)

__device__ __forceinline__ u16 f2bf(float f) {
  unsigned u = __builtin_bit_cast(unsigned, f);
  u += 0x7FFFu + ((u >> 16) & 1u);   // RNE
  return (u16)(u >> 16);
}

// async global->LDS, 16B per lane; LDS dest = wave-uniform base + lane*16
__device__ __forceinline__ void async_ld16(const void* g, void* lds) {
  __builtin_amdgcn_global_load_lds(
      (const __attribute__((address_space(1))) unsigned int*)(g),
      (__attribute__((address_space(3))) unsigned int*)(lds), 16, 0, 0);
}

// ---------------------------------------------------------------------------
// Wt[w][n][k] = bf16(W_w[k][n])  (transpose+convert so GEMM B-frags are k-contiguous)
__global__ __launch_bounds__(256) void prep_w(const float* __restrict__ Wq,
                                              const float* __restrict__ Wk,
                                              const float* __restrict__ Wv,
                                              u16* __restrict__ Wt) {
  int g = blockIdx.x * 256 + threadIdx.x;   // 3*128*256 = 98304 threads
  int w = g >> 15;
  int rem = g & 32767;
  int n = rem >> 8;
  int k0 = (rem & 255) * 8;
  const float* W = (w == 0) ? Wq : (w == 1) ? Wk : Wv;
  unsigned pk[4];
  for (int i = 0; i < 4; ++i) {
    u16 lo = f2bf(W[(size_t)(k0 + 2 * i) * DDIM + n]);
    u16 hi = f2bf(W[(size_t)(k0 + 2 * i + 1) * DDIM + n]);
    pk[i] = (unsigned)lo | ((unsigned)hi << 16);
  }
  uint4 v; v.x = pk[0]; v.y = pk[1]; v.z = pk[2]; v.w = pk[3];
  *(uint4*)(Wt + ((size_t)(w * DDIM + n) * EDIM + k0)) = v;
}

// ---------------------------------------------------------------------------
// q/k/v = x @ W  (bf16 MFMA, fp32 accumulate). Tile 128x128, BK=64, 4 waves 2x2.
__global__ __launch_bounds__(256, 1) void qkv_gemm(const float* __restrict__ x,
                                                   const u16* __restrict__ Wt,
                                                   u16* __restrict__ qkvb) {
  __shared__ u16 As[128 * 64];   // [m][k] bf16
  __shared__ u16 Bs[128 * 64];   // [n][k] bf16
  const int tid = threadIdx.x, lane = tid & 63, wave = tid >> 6;
  const int quad = lane >> 4;
  const int m0 = blockIdx.x * 128;
  const int which = blockIdx.y;
  const int wm = wave & 1, wn = wave >> 1;

  const f32x4 zero = {0.f, 0.f, 0.f, 0.f};
  f32x4 acc[4][4];
  for (int mi = 0; mi < 4; ++mi)
    for (int ni = 0; ni < 4; ++ni) acc[mi][ni] = zero;

  const u16* wbase = Wt + (size_t)which * DDIM * EDIM;

  for (int kt = 0; kt < EDIM / 64; ++kt) {
    const int k0 = kt * 64;
    __syncthreads();
    // B tile via global_load_lds: 128 rows x 128B; 8 rows per wave-instr
    for (int e = 0; e < 4; ++e) {
      int n0 = (wave * 4 + e) * 8;
      int n = n0 + (lane >> 3);
      const char* g = (const char*)(wbase + (size_t)n * EDIM + k0) + (lane & 7) * 16;
      async_ld16(g, (char*)Bs + n0 * 128);
    }
    // A tile: fp32 load + convert
    for (int i = 0; i < 8; ++i) {
      int c = tid + i * 256;
      int row = c >> 4, f4 = c & 15;
      const float4 v = *(const float4*)(x + (size_t)(m0 + row) * EDIM + k0 + f4 * 4);
      uint2 pk;
      pk.x = (unsigned)f2bf(v.x) | ((unsigned)f2bf(v.y) << 16);
      pk.y = (unsigned)f2bf(v.z) | ((unsigned)f2bf(v.w) << 16);
      *(uint2*)(As + row * 64 + f4 * 4) = pk;
    }
    __builtin_amdgcn_s_waitcnt(0);
    __syncthreads();
    for (int ks = 0; ks < 2; ++ks) {
      const int kk = ks * 32 + quad * 8;
      bf16x8 af[4], bfr[4];
      for (int mi = 0; mi < 4; ++mi)
        af[mi] = *(const bf16x8*)(As + (wm * 64 + mi * 16 + (lane & 15)) * 64 + kk);
      for (int ni = 0; ni < 4; ++ni)
        bfr[ni] = *(const bf16x8*)(Bs + (wn * 64 + ni * 16 + (lane & 15)) * 64 + kk);
      for (int mi = 0; mi < 4; ++mi)
        for (int ni = 0; ni < 4; ++ni)
          acc[mi][ni] = __builtin_amdgcn_mfma_f32_16x16x32_bf16(af[mi], bfr[ni], acc[mi][ni], 0, 0, 0);
    }
  }
  u16* ob = qkvb + (size_t)which * MROWS * DDIM;
  for (int mi = 0; mi < 4; ++mi)
    for (int ni = 0; ni < 4; ++ni) {
      int col = wn * 64 + ni * 16 + (lane & 15);
      for (int r = 0; r < 4; ++r) {
        int row = m0 + wm * 64 + mi * 16 + quad * 4 + r;   // C/D: row = quad*4+reg
        ob[(size_t)row * DDIM + col] = f2bf(acc[mi][ni][r]);
      }
    }
}

// ---------------------------------------------------------------------------
// vbT[b][d][t] = vb[b][t][d]
__global__ __launch_bounds__(256) void transpose_v(const u16* __restrict__ vb,
                                                   u16* __restrict__ vbT) {
  __shared__ u16 tile[128 * 136];  // +8 pad
  const int tid = threadIdx.x;
  const int t0 = blockIdx.x * 128, b = blockIdx.y;
  for (int i = 0; i < 8; ++i) {
    int c = tid + i * 256;
    int tl = c >> 4, ch = c & 15;
    uint4 v = *(const uint4*)(vb + ((size_t)(b * TLEN + t0 + tl) * DDIM + ch * 8));
    *(uint4*)(tile + tl * 136 + ch * 8) = v;
  }
  __syncthreads();
  for (int i = 0; i < 8; ++i) {
    int c = tid + i * 256;
    int d = c >> 4, ch = c & 15;
    unsigned pk[4];
    for (int j = 0; j < 4; ++j) {
      u16 lo = tile[(ch * 8 + 2 * j) * 136 + d];
      u16 hi = tile[(ch * 8 + 2 * j + 1) * 136 + d];
      pk[j] = (unsigned)lo | ((unsigned)hi << 16);
    }
    uint4 v; v.x = pk[0]; v.y = pk[1]; v.z = pk[2]; v.w = pk[3];
    *(uint4*)(vbT + ((size_t)(b * DDIM + d) * TLEN + t0 + ch * 8)) = v;
  }
}

// ---------------------------------------------------------------------------
// denom[b][j] = sum_{i>=j} exp(scale * q_i . k_j)   (softmax over QUERY axis)
__global__ __launch_bounds__(256, 1) void colsum_k(const u16* __restrict__ qb,
                                                   const u16* __restrict__ kb,
                                                   float* __restrict__ denom) {
  __shared__ u16 Ks[128 * 128];
  __shared__ u16 Qs[128 * 128];
  const int tid = threadIdx.x, lane = tid & 63, wave = tid >> 6;
  const int quad = lane >> 4;
  const int jt = blockIdx.x, b = blockIdx.y;
  const int j0 = jt * 128;

  {  // stage K tile once
    const char* gk = (const char*)(kb + (size_t)(b * TLEN + j0) * DDIM);
    for (int e = 0; e < 8; ++e) {
      int rb = (wave * 8 + e) * 4;
      async_ld16(gk + (rb + quad) * 256 + (lane & 15) * 16, (char*)Ks + rb * 256);
    }
  }
  float csum[8];
  for (int ni = 0; ni < 8; ++ni) csum[ni] = 0.f;
  const f32x4 zero = {0.f, 0.f, 0.f, 0.f};

  for (int it = jt; it < NT; ++it) {
    const int i0 = it * 128;
    __syncthreads();
    {
      const char* gq = (const char*)(qb + (size_t)(b * TLEN + i0) * DDIM);
      for (int e = 0; e < 8; ++e) {
        int rb = (wave * 8 + e) * 4;
        async_ld16(gq + (rb + quad) * 256 + (lane & 15) * 16, (char*)Qs + rb * 256);
      }
    }
    __builtin_amdgcn_s_waitcnt(0);
    __syncthreads();
    f32x4 acc[2][8];
    for (int mi = 0; mi < 2; ++mi)
      for (int ni = 0; ni < 8; ++ni) acc[mi][ni] = zero;
    for (int ks = 0; ks < 4; ++ks) {
      const int kk = ks * 32 + quad * 8;
      bf16x8 af[2], bfr[8];
      for (int mi = 0; mi < 2; ++mi)
        af[mi] = *(const bf16x8*)(Qs + (wave * 32 + mi * 16 + (lane & 15)) * 128 + kk);
      for (int ni = 0; ni < 8; ++ni)
        bfr[ni] = *(const bf16x8*)(Ks + (ni * 16 + (lane & 15)) * 128 + kk);
      for (int mi = 0; mi < 2; ++mi)
        for (int ni = 0; ni < 8; ++ni)
          acc[mi][ni] = __builtin_amdgcn_mfma_f32_16x16x32_bf16(af[mi], bfr[ni], acc[mi][ni], 0, 0, 0);
    }
    const bool diag = (it == jt);
    for (int mi = 0; mi < 2; ++mi)
      for (int ni = 0; ni < 8; ++ni)
        for (int r = 0; r < 4; ++r) {
          float e = exp2f(C1F * acc[mi][ni][r]);
          if (diag) {
            int ig = i0 + wave * 32 + mi * 16 + quad * 4 + r;
            int jg = j0 + ni * 16 + (lane & 15);
            if (ig < jg) e = 0.f;
          }
          csum[ni] += e;
        }
  }
  // reduce lanes {n, n+16, n+32, n+48}
  for (int ni = 0; ni < 8; ++ni) {
    csum[ni] += __shfl_xor(csum[ni], 16, 64);
    csum[ni] += __shfl_xor(csum[ni], 32, 64);
  }
  __syncthreads();                 // all waves done reading Qs
  float* red = (float*)Qs;         // overlay cross-wave reduce buffer on Qs
  if (lane < 16)
    for (int ni = 0; ni < 8; ++ni)
      red[wave * 128 + ni * 16 + lane] = csum[ni];
  __syncthreads();
  if (tid < 128)
    denom[(size_t)b * TLEN + j0 + tid] =
        red[tid] + red[128 + tid] + red[256 + tid] + red[384 + tid];
}

// ---------------------------------------------------------------------------
// out[b][i][:] = sum_{j<=i} exp(scale*s_ij)/denom[j] * v[j][:]
__global__ __launch_bounds__(256, 1) void attn_k(const u16* __restrict__ qb,
                                                 const u16* __restrict__ kb,
                                                 const u16* __restrict__ vbT,
                                                 const float* __restrict__ denom,
                                                 float* __restrict__ out) {
  __shared__ u16 Ks[128 * 128];   // doubles as P buffer (A-layout [i][j]) after QK
  __shared__ u16 Vts[128 * 128];  // [d][j]
  const int tid = threadIdx.x, lane = tid & 63, wave = tid >> 6;
  const int quad = lane >> 4;
  const int it = blockIdx.x, b = blockIdx.y;
  const int i0 = it * 128;

  // stage Q tile (into Ks buffer), pull fragments to registers, then release
  {
    const char* gq = (const char*)(qb + (size_t)(b * TLEN + i0) * DDIM);
    for (int e = 0; e < 8; ++e) {
      int rb = (wave * 8 + e) * 4;
      async_ld16(gq + (rb + quad) * 256 + (lane & 15) * 16, (char*)Ks + rb * 256);
    }
  }
  __builtin_amdgcn_s_waitcnt(0);
  __syncthreads();
  bf16x8 qf[2][4];
  for (int mi = 0; mi < 2; ++mi)
    for (int ks = 0; ks < 4; ++ks)
      qf[mi][ks] = *(const bf16x8*)(Ks + (wave * 32 + mi * 16 + (lane & 15)) * 128 + ks * 32 + quad * 8);

  const f32x4 zero = {0.f, 0.f, 0.f, 0.f};
  f32x4 accO[2][8];
  for (int mi = 0; mi < 2; ++mi)
    for (int ni = 0; ni < 8; ++ni) accO[mi][ni] = zero;

  for (int jt = 0; jt <= it; ++jt) {
    const int j0 = jt * 128;
    __syncthreads();   // (a) qf reads / previous-iter P+V reads complete
    {
      const char* gk = (const char*)(kb + (size_t)(b * TLEN + j0) * DDIM);
      const char* gv = (const char*)vbT + ((size_t)b * DDIM * TLEN + j0) * 2;
      for (int e = 0; e < 8; ++e) {
        int rb = (wave * 8 + e) * 4;
        async_ld16(gk + (rb + quad) * 256 + (lane & 15) * 16, (char*)Ks + rb * 256);
        async_ld16(gv + (size_t)(rb + quad) * (TLEN * 2) + (lane & 15) * 16, (char*)Vts + rb * 256);
      }
    }
    __builtin_amdgcn_s_waitcnt(0);
    __syncthreads();   // (b) staging visible
    f32x4 accS[2][8];
    for (int mi = 0; mi < 2; ++mi)
      for (int ni = 0; ni < 8; ++ni) accS[mi][ni] = zero;
    for (int ks = 0; ks < 4; ++ks) {
      const int kk = ks * 32 + quad * 8;
      bf16x8 bfr[8];
      for (int ni = 0; ni < 8; ++ni)
        bfr[ni] = *(const bf16x8*)(Ks + (ni * 16 + (lane & 15)) * 128 + kk);
      for (int mi = 0; mi < 2; ++mi)
        for (int ni = 0; ni < 8; ++ni)
          accS[mi][ni] = __builtin_amdgcn_mfma_f32_16x16x32_bf16(qf[mi][ks], bfr[ni], accS[mi][ni], 0, 0, 0);
    }
    float rdr[8];
    for (int ni = 0; ni < 8; ++ni)
      rdr[ni] = 1.0f / denom[(size_t)b * TLEN + j0 + ni * 16 + (lane & 15)];
    __syncthreads();   // (c) all QK reads of Ks done before overwriting with P
    const bool diag = (jt == it);
    for (int mi = 0; mi < 2; ++mi)
      for (int ni = 0; ni < 8; ++ni)
        for (int r = 0; r < 4; ++r) {
          float p = exp2f(C1F * accS[mi][ni][r]) * rdr[ni];
          int rrow = wave * 32 + mi * 16 + quad * 4 + r;
          int ccol = ni * 16 + (lane & 15);
          if (diag && (i0 + rrow) < (j0 + ccol)) p = 0.f;
          Ks[rrow * 128 + ccol] = f2bf(p);   // P in A-operand layout [i][j]
        }
    __syncthreads();   // (d) P visible
    for (int ks = 0; ks < 4; ++ks) {
      const int kk = ks * 32 + quad * 8;
      bf16x8 af[2], bfr[8];
      for (int mi = 0; mi < 2; ++mi)
        af[mi] = *(const bf16x8*)(Ks + (wave * 32 + mi * 16 + (lane & 15)) * 128 + kk);
      for (int ni = 0; ni < 8; ++ni)
        bfr[ni] = *(const bf16x8*)(Vts + (ni * 16 + (lane & 15)) * 128 + kk);
      for (int mi = 0; mi < 2; ++mi)
        for (int ni = 0; ni < 8; ++ni)
          accO[mi][ni] = __builtin_amdgcn_mfma_f32_16x16x32_bf16(af[mi], bfr[ni], accO[mi][ni], 0, 0, 0);
    }
  }
  for (int mi = 0; mi < 2; ++mi)
    for (int ni = 0; ni < 8; ++ni) {
      int ccol = ni * 16 + (lane & 15);
      for (int r = 0; r < 4; ++r) {
        int rrow = i0 + wave * 32 + mi * 16 + quad * 4 + r;
        out[((size_t)b * TLEN + rrow) * DDIM + ccol] = accO[mi][ni][r];
      }
    }
}

// ---------------------------------------------------------------------------
extern "C" void kernel_launch(void* const* d_in, const int* in_sizes, int n_in,
                              void* d_out, int out_size, void* d_ws, size_t ws_size,
                              hipStream_t stream) {
  const float* x  = (const float*)d_in[0];
  const float* Wq = (const float*)d_in[1];
  const float* Wk = (const float*)d_in[2];
  const float* Wv = (const float*)d_in[3];
  float* out = (float*)d_out;

  // workspace layout (bf16 unless noted): ~33.7 MB total
  u16* qb  = (u16*)d_ws;                       // [32768][128]
  u16* kb  = qb  + (size_t)MROWS * DDIM;
  u16* vb  = kb  + (size_t)MROWS * DDIM;
  u16* vbT = vb  + (size_t)MROWS * DDIM;       // [8][128][4096]
  u16* Wt  = vbT + (size_t)MROWS * DDIM;       // [3][128][2048]
  float* denom = (float*)(Wt + (size_t)3 * DDIM * EDIM);  // [8][4096] fp32

  hipLaunchKernelGGL(prep_w, dim3(384), dim3(256), 0, stream, Wq, Wk, Wv, Wt);
  hipLaunchKernelGGL(qkv_gemm, dim3(256, 3), dim3(256), 0, stream, x, Wt, qb);
  hipLaunchKernelGGL(transpose_v, dim3(NT, BSZ), dim3(256), 0, stream, vb, vbT);
  hipLaunchKernelGGL(colsum_k, dim3(NT, BSZ), dim3(256), 0, stream, qb, kb, denom);
  hipLaunchKernelGGL(attn_k, dim3(NT, BSZ), dim3(256), 0, stream, qb, kb, vbT, denom, out);
}

// Round 2
// 881.739 us; speedup vs baseline: 1.0472x; 1.0472x over previous
//
#include <hip/hip_runtime.h>
#include <hip/hip_bf16.h>

#define TLEN 4096
#define EDIM 2048
#define DDIM 128
#define BSZ  8
#define NT   32            // TLEN/128
#define MROWS (BSZ*TLEN)   // 32768

typedef unsigned short u16;
typedef __attribute__((ext_vector_type(8))) short bf16x8;  // 8 bf16 in 4 VGPRs
typedef __attribute__((ext_vector_type(4))) float f32x4;

// exp(scale * s) = exp2(C1 * s), scale = 1/sqrt(128)
#define C1F (0.08838834764831845f * 1.4426950408889634f)

__device__ __forceinline__ u16 f2bf(float f) {
  unsigned u = __builtin_bit_cast(unsigned, f);
  u += 0x7FFFu + ((u >> 16) & 1u);   // RNE
  return (u16)(u >> 16);
}

// async global->LDS, 16B per lane; LDS dest = wave-uniform base + lane*16
__device__ __forceinline__ void async_ld16(const void* g, void* lds) {
  __builtin_amdgcn_global_load_lds(
      (const __attribute__((address_space(1))) unsigned int*)(g),
      (__attribute__((address_space(3))) unsigned int*)(lds), 16, 0, 0);
}

// XOR-swizzled byte offset: 256B rows (16 x 16B chunks). chunk ^= row&15 makes
// stride-256B fragment reads 2-way bank-spread (free) instead of 16-way.
__device__ __forceinline__ int swz16(int row, int chunk) {
  return row * 256 + ((chunk ^ (row & 15)) << 4);
}
// 128B rows (8 x 16B chunks)
__device__ __forceinline__ int swz8(int row, int chunk) {
  return row * 128 + ((chunk ^ (row & 7)) << 4);
}

// ---------------------------------------------------------------------------
// zero out[] (atomic-accumulated) and denom[]
__global__ __launch_bounds__(256) void zero_f32(float* __restrict__ out,
                                                float* __restrict__ denom) {
  size_t i = (size_t)blockIdx.x * 256 + threadIdx.x;
  float4 z = {0.f, 0.f, 0.f, 0.f};
  if (i < (size_t)MROWS * DDIM / 4) ((float4*)out)[i] = z;
  if (i < (size_t)BSZ * TLEN / 4) ((float4*)denom)[i] = z;
}

// ---------------------------------------------------------------------------
// Wt[w][n][k] = bf16(W_w[k][n])
__global__ __launch_bounds__(256) void prep_w(const float* __restrict__ Wq,
                                              const float* __restrict__ Wk,
                                              const float* __restrict__ Wv,
                                              u16* __restrict__ Wt) {
  int g = blockIdx.x * 256 + threadIdx.x;
  int w = g >> 15;
  int rem = g & 32767;
  int n = rem >> 8;
  int k0 = (rem & 255) * 8;
  const float* W = (w == 0) ? Wq : (w == 1) ? Wk : Wv;
  unsigned pk[4];
  for (int i = 0; i < 4; ++i) {
    u16 lo = f2bf(W[(size_t)(k0 + 2 * i) * DDIM + n]);
    u16 hi = f2bf(W[(size_t)(k0 + 2 * i + 1) * DDIM + n]);
    pk[i] = (unsigned)lo | ((unsigned)hi << 16);
  }
  uint4 v; v.x = pk[0]; v.y = pk[1]; v.z = pk[2]; v.w = pk[3];
  *(uint4*)(Wt + ((size_t)(w * DDIM + n) * EDIM + k0)) = v;
}

// ---------------------------------------------------------------------------
// Fused q,k,v GEMM: one pass over x. M-tile 128, N=384 (all 3 heads), BK=64.
// 512 threads = 8 waves (2x4), per-wave 64x96. A fp32->bf16 via reg prefetch.
__global__ __launch_bounds__(512, 2) void qkv_gemm(const float* __restrict__ x,
                                                   const u16* __restrict__ Wt,
                                                   u16* __restrict__ qkvb) {
  __shared__ u16 As[128 * 64];   // 16 KB, swizzled 128B rows
  __shared__ u16 Bs[384 * 64];   // 48 KB, swizzled 128B rows
  const int tid = threadIdx.x, lane = tid & 63, wave = tid >> 6;
  const int quad = lane >> 4, l15 = lane & 15;
  const int m0 = blockIdx.x * 128;
  const int wm = wave & 1, wn = wave >> 1;   // 2 x 4 wave grid

  const f32x4 zero = {0.f, 0.f, 0.f, 0.f};
  f32x4 acc[4][6];
  for (int mi = 0; mi < 4; ++mi)
    for (int ni = 0; ni < 6; ++ni) acc[mi][ni] = zero;

  int arow[4], af4[4];
  for (int i = 0; i < 4; ++i) {
    int c = i * 512 + tid;
    arow[i] = c >> 4;           // 128 rows x 16 float4
    af4[i] = c & 15;
  }
  float4 ap[4];
#define LOADA(KT)                                                            \
  for (int i = 0; i < 4; ++i)                                                \
    ap[i] = *(const float4*)(x + (size_t)(m0 + arow[i]) * EDIM + (KT)*64 +   \
                             af4[i] * 4);
  LOADA(0)

  for (int kt = 0; kt < EDIM / 64; ++kt) {
    __syncthreads();   // previous MFMA reads done
    // store A(kt) swizzled (8B granules: chunk = f4>>1, half = f4&1)
    for (int i = 0; i < 4; ++i) {
      uint2 pk;
      pk.x = (unsigned)f2bf(ap[i].x) | ((unsigned)f2bf(ap[i].y) << 16);
      pk.y = (unsigned)f2bf(ap[i].z) | ((unsigned)f2bf(ap[i].w) << 16);
      *(uint2*)((char*)As + swz8(arow[i], af4[i] >> 1) + (af4[i] & 1) * 8) = pk;
    }
    // stage B(kt): 384 rows x 128B, 8 rows per instr, 6 instrs per wave
    {
      const int k0 = kt * 64;
      for (int e = 0; e < 6; ++e) {
        int rb = (wave * 6 + e) * 8;
        int r = rb + (lane >> 3);
        int c = (lane & 7) ^ (r & 7);
        async_ld16((const char*)(Wt + (size_t)r * EDIM + k0) + c * 16,
                   (char*)Bs + rb * 128);
      }
    }
    __builtin_amdgcn_s_waitcnt(0);
    __syncthreads();
    if (kt + 1 < EDIM / 64) { LOADA(kt + 1) }   // in flight during MFMA
    for (int ks = 0; ks < 2; ++ks) {
      const int ch = ks * 4 + quad;
      bf16x8 afr[4], bfr[6];
      for (int mi = 0; mi < 4; ++mi)
        afr[mi] = *(const bf16x8*)((char*)As + swz8(wm * 64 + mi * 16 + l15, ch));
      for (int ni = 0; ni < 6; ++ni)
        bfr[ni] = *(const bf16x8*)((char*)Bs + swz8(wn * 96 + ni * 16 + l15, ch));
      for (int mi = 0; mi < 4; ++mi)
        for (int ni = 0; ni < 6; ++ni)
          acc[mi][ni] = __builtin_amdgcn_mfma_f32_16x16x32_bf16(afr[mi], bfr[ni], acc[mi][ni], 0, 0, 0);
    }
  }
#undef LOADA
  for (int mi = 0; mi < 4; ++mi)
    for (int ni = 0; ni < 6; ++ni) {
      int n = wn * 96 + ni * 16 + l15;
      u16* ob = qkvb + (size_t)(n >> 7) * MROWS * DDIM;
      int nc = n & 127;
      for (int r = 0; r < 4; ++r) {
        int row = m0 + wm * 64 + mi * 16 + quad * 4 + r;
        ob[(size_t)row * DDIM + nc] = f2bf(acc[mi][ni][r]);
      }
    }
}

// ---------------------------------------------------------------------------
// vbT[b][d][t] = vb[b][t][d]
__global__ __launch_bounds__(256) void transpose_v(const u16* __restrict__ vb,
                                                   u16* __restrict__ vbT) {
  __shared__ u16 tile[128 * 136];
  const int tid = threadIdx.x;
  const int t0 = blockIdx.x * 128, b = blockIdx.y;
  for (int i = 0; i < 8; ++i) {
    int c = tid + i * 256;
    int tl = c >> 4, ch = c & 15;
    uint4 v = *(const uint4*)(vb + ((size_t)(b * TLEN + t0 + tl) * DDIM + ch * 8));
    *(uint4*)(tile + tl * 136 + ch * 8) = v;
  }
  __syncthreads();
  for (int i = 0; i < 8; ++i) {
    int c = tid + i * 256;
    int d = c >> 4, ch = c & 15;
    unsigned pk[4];
    for (int j = 0; j < 4; ++j) {
      u16 lo = tile[(ch * 8 + 2 * j) * 136 + d];
      u16 hi = tile[(ch * 8 + 2 * j + 1) * 136 + d];
      pk[j] = (unsigned)lo | ((unsigned)hi << 16);
    }
    uint4 v; v.x = pk[0]; v.y = pk[1]; v.z = pk[2]; v.w = pk[3];
    *(uint4*)(vbT + ((size_t)(b * DDIM + d) * TLEN + t0 + ch * 8)) = v;
  }
}

// ---------------------------------------------------------------------------
// denom[b][j] += sum over chunk of i-tiles of exp(scale*q_i.k_j), i>=j.
// Grid (jt, ic, b); chunk = 4 i-tiles; atomicAdd into denom.
__global__ __launch_bounds__(256, 2) void colsum_k(const u16* __restrict__ qb,
                                                   const u16* __restrict__ kb,
                                                   float* __restrict__ denom) {
  __shared__ u16 Ks[128 * 128];
  __shared__ u16 Qs[128 * 128];
  const int tid = threadIdx.x, lane = tid & 63, wave = tid >> 6;
  const int quad = lane >> 4, l15 = lane & 15;
  const int jt = blockIdx.x, ic = blockIdx.y, b = blockIdx.z;
  const int itBeg = jt + ic * 4;
  if (itBeg >= NT) return;
  const int itEnd = (itBeg + 4 < NT) ? itBeg + 4 : NT;
  const int j0 = jt * 128;

  {  // stage K tile once (swizzled)
    const char* gk = (const char*)(kb + (size_t)(b * TLEN + j0) * DDIM);
    for (int e = 0; e < 8; ++e) {
      int rb = (wave * 8 + e) * 4;
      int r = rb + quad;
      int c = l15 ^ (r & 15);
      async_ld16(gk + r * 256 + c * 16, (char*)Ks + rb * 256);
    }
  }
  float csum[8];
  for (int ni = 0; ni < 8; ++ni) csum[ni] = 0.f;
  const f32x4 zero = {0.f, 0.f, 0.f, 0.f};

  for (int it = itBeg; it < itEnd; ++it) {
    const int i0 = it * 128;
    __syncthreads();
    {
      const char* gq = (const char*)(qb + (size_t)(b * TLEN + i0) * DDIM);
      for (int e = 0; e < 8; ++e) {
        int rb = (wave * 8 + e) * 4;
        int r = rb + quad;
        int c = l15 ^ (r & 15);
        async_ld16(gq + r * 256 + c * 16, (char*)Qs + rb * 256);
      }
    }
    __builtin_amdgcn_s_waitcnt(0);
    __syncthreads();
    f32x4 acc[2][8];
    for (int mi = 0; mi < 2; ++mi)
      for (int ni = 0; ni < 8; ++ni) acc[mi][ni] = zero;
    for (int ks = 0; ks < 4; ++ks) {
      const int ch = ks * 4 + quad;
      bf16x8 af[2], bfr[8];
      for (int mi = 0; mi < 2; ++mi)
        af[mi] = *(const bf16x8*)((char*)Qs + swz16(wave * 32 + mi * 16 + l15, ch));
      for (int ni = 0; ni < 8; ++ni)
        bfr[ni] = *(const bf16x8*)((char*)Ks + swz16(ni * 16 + l15, ch));
      for (int mi = 0; mi < 2; ++mi)
        for (int ni = 0; ni < 8; ++ni)
          acc[mi][ni] = __builtin_amdgcn_mfma_f32_16x16x32_bf16(af[mi], bfr[ni], acc[mi][ni], 0, 0, 0);
    }
    const bool diag = (it == jt);
    for (int mi = 0; mi < 2; ++mi)
      for (int ni = 0; ni < 8; ++ni)
        for (int r = 0; r < 4; ++r) {
          float e = exp2f(C1F * acc[mi][ni][r]);
          if (diag) {
            int ig = i0 + wave * 32 + mi * 16 + quad * 4 + r;
            int jg = j0 + ni * 16 + l15;
            if (ig < jg) e = 0.f;
          }
          csum[ni] += e;
        }
  }
  for (int ni = 0; ni < 8; ++ni) {
    csum[ni] += __shfl_xor(csum[ni], 16, 64);
    csum[ni] += __shfl_xor(csum[ni], 32, 64);
  }
  __syncthreads();
  float* red = (float*)Qs;
  if (lane < 16)
    for (int ni = 0; ni < 8; ++ni)
      red[wave * 128 + ni * 16 + lane] = csum[ni];
  __syncthreads();
  if (tid < 128)
    atomicAdd(&denom[(size_t)b * TLEN + j0 + tid],
              red[tid] + red[128 + tid] + red[256 + tid] + red[384 + tid]);
}

// ---------------------------------------------------------------------------
// out[b][i][:] += sum over chunk of j-tiles of P_ij * v[j][:].
// Grid (it, jc, b); chunk = 4 j-tiles; fp32 atomicAdd into out.
__global__ __launch_bounds__(256, 2) void attn_k(const u16* __restrict__ qb,
                                                 const u16* __restrict__ kb,
                                                 const u16* __restrict__ vbT,
                                                 const float* __restrict__ denom,
                                                 float* __restrict__ out) {
  __shared__ u16 Ks[128 * 128];   // K tile, then P tile (A-layout, swizzled)
  __shared__ u16 Vts[128 * 128];  // [d][j] swizzled
  const int tid = threadIdx.x, lane = tid & 63, wave = tid >> 6;
  const int quad = lane >> 4, l15 = lane & 15;
  const int it = blockIdx.x, jc = blockIdx.y, b = blockIdx.z;
  if (jc * 4 > it) return;
  const int jtBeg = jc * 4;
  const int jtEnd = (jtBeg + 4 < it + 1) ? jtBeg + 4 : it + 1;
  const int i0 = it * 128;

  {  // stage Q via Ks, pull fragments to registers
    const char* gq = (const char*)(qb + (size_t)(b * TLEN + i0) * DDIM);
    for (int e = 0; e < 8; ++e) {
      int rb = (wave * 8 + e) * 4;
      int r = rb + quad;
      int c = l15 ^ (r & 15);
      async_ld16(gq + r * 256 + c * 16, (char*)Ks + rb * 256);
    }
  }
  __builtin_amdgcn_s_waitcnt(0);
  __syncthreads();
  bf16x8 qf[2][4];
  for (int mi = 0; mi < 2; ++mi)
    for (int ks = 0; ks < 4; ++ks)
      qf[mi][ks] = *(const bf16x8*)((char*)Ks + swz16(wave * 32 + mi * 16 + l15, ks * 4 + quad));

  const f32x4 zero = {0.f, 0.f, 0.f, 0.f};
  f32x4 accO[2][8];
  for (int mi = 0; mi < 2; ++mi)
    for (int ni = 0; ni < 8; ++ni) accO[mi][ni] = zero;

  for (int jt = jtBeg; jt < jtEnd; ++jt) {
    const int j0 = jt * 128;
    __syncthreads();   // (a) prior reads of Ks/Vts (and qf pulls) complete
    {
      const char* gk = (const char*)(kb + (size_t)(b * TLEN + j0) * DDIM);
      const char* gv = (const char*)(vbT + (size_t)b * DDIM * TLEN + j0);
      for (int e = 0; e < 8; ++e) {
        int rb = (wave * 8 + e) * 4;
        int r = rb + quad;
        int c = l15 ^ (r & 15);
        async_ld16(gk + r * 256 + c * 16, (char*)Ks + rb * 256);
        async_ld16(gv + (size_t)r * (TLEN * 2) + c * 16, (char*)Vts + rb * 256);
      }
    }
    __builtin_amdgcn_s_waitcnt(0);
    __syncthreads();   // (b) staging visible
    f32x4 accS[2][8];
    for (int mi = 0; mi < 2; ++mi)
      for (int ni = 0; ni < 8; ++ni) accS[mi][ni] = zero;
    for (int ks = 0; ks < 4; ++ks) {
      const int ch = ks * 4 + quad;
      bf16x8 bfr[8];
      for (int ni = 0; ni < 8; ++ni)
        bfr[ni] = *(const bf16x8*)((char*)Ks + swz16(ni * 16 + l15, ch));
      for (int mi = 0; mi < 2; ++mi)
        for (int ni = 0; ni < 8; ++ni)
          accS[mi][ni] = __builtin_amdgcn_mfma_f32_16x16x32_bf16(qf[mi][ks], bfr[ni], accS[mi][ni], 0, 0, 0);
    }
    float rdr[8];
    for (int ni = 0; ni < 8; ++ni)
      rdr[ni] = 1.0f / denom[(size_t)b * TLEN + j0 + ni * 16 + l15];
    __syncthreads();   // (c) QK reads of Ks done before P overwrite
    const bool diag = (jt == it);
    for (int mi = 0; mi < 2; ++mi)
      for (int ni = 0; ni < 8; ++ni)
        for (int r = 0; r < 4; ++r) {
          float p = exp2f(C1F * accS[mi][ni][r]) * rdr[ni];
          int rrow = wave * 32 + mi * 16 + quad * 4 + r;
          int ccol = ni * 16 + l15;
          if (diag && (i0 + rrow) < (j0 + ccol)) p = 0.f;
          *(u16*)((char*)Ks + swz16(rrow, ccol >> 3) + (ccol & 7) * 2) = f2bf(p);
        }
    __syncthreads();   // (d) P visible
    for (int ks = 0; ks < 4; ++ks) {
      const int ch = ks * 4 + quad;
      bf16x8 af[2], bfr[8];
      for (int mi = 0; mi < 2; ++mi)
        af[mi] = *(const bf16x8*)((char*)Ks + swz16(wave * 32 + mi * 16 + l15, ch));
      for (int ni = 0; ni < 8; ++ni)
        bfr[ni] = *(const bf16x8*)((char*)Vts + swz16(ni * 16 + l15, ch));
      for (int mi = 0; mi < 2; ++mi)
        for (int ni = 0; ni < 8; ++ni)
          accO[mi][ni] = __builtin_amdgcn_mfma_f32_16x16x32_bf16(af[mi], bfr[ni], accO[mi][ni], 0, 0, 0);
    }
  }
  const bool excl = (it < 4);   // only one contributing block -> plain store
  for (int mi = 0; mi < 2; ++mi)
    for (int ni = 0; ni < 8; ++ni) {
      int ccol = ni * 16 + l15;
      for (int r = 0; r < 4; ++r) {
        int rrow = i0 + wave * 32 + mi * 16 + quad * 4 + r;
        float* dst = &out[((size_t)b * TLEN + rrow) * DDIM + ccol];
        if (excl) *dst = accO[mi][ni][r];
        else atomicAdd(dst, accO[mi][ni][r]);
      }
    }
}

// ---------------------------------------------------------------------------
extern "C" void kernel_launch(void* const* d_in, const int* in_sizes, int n_in,
                              void* d_out, int out_size, void* d_ws, size_t ws_size,
                              hipStream_t stream) {
  const float* x  = (const float*)d_in[0];
  const float* Wq = (const float*)d_in[1];
  const float* Wk = (const float*)d_in[2];
  const float* Wv = (const float*)d_in[3];
  float* out = (float*)d_out;

  u16* qb  = (u16*)d_ws;                       // [32768][128] bf16
  u16* kb  = qb  + (size_t)MROWS * DDIM;
  u16* vb  = kb  + (size_t)MROWS * DDIM;
  u16* vbT = vb  + (size_t)MROWS * DDIM;       // [8][128][4096]
  u16* Wt  = vbT + (size_t)MROWS * DDIM;       // [3][128][2048]
  float* denom = (float*)(Wt + (size_t)3 * DDIM * EDIM);  // [8][4096] fp32

  hipLaunchKernelGGL(zero_f32, dim3(4096), dim3(256), 0, stream, out, denom);
  hipLaunchKernelGGL(prep_w, dim3(384), dim3(256), 0, stream, Wq, Wk, Wv, Wt);
  hipLaunchKernelGGL(qkv_gemm, dim3(256), dim3(512), 0, stream, x, Wt, qb);
  hipLaunchKernelGGL(transpose_v, dim3(NT, BSZ), dim3(256), 0, stream, vb, vbT);
  hipLaunchKernelGGL(colsum_k, dim3(NT, 8, BSZ), dim3(256), 0, stream, qb, kb, denom);
  hipLaunchKernelGGL(attn_k, dim3(NT, 8, BSZ), dim3(256), 0, stream, qb, kb, vbT, denom, out);
}

// Round 3
// 623.490 us; speedup vs baseline: 1.4809x; 1.4142x over previous
//
#include <hip/hip_runtime.h>
#include <hip/hip_bf16.h>

#define TLEN 4096
#define EDIM 2048
#define DDIM 128
#define BSZ  8
#define NT   32            // TLEN/128
#define MROWS (BSZ*TLEN)   // 32768
#define NSLOT 528          // NT*(NT+1)/2 lower-tri tiles per batch

typedef unsigned short u16;
typedef __attribute__((ext_vector_type(8))) short bf16x8;  // 8 bf16 in 4 VGPRs
typedef __attribute__((ext_vector_type(4))) float f32x4;

// exp(scale * s) = exp2(C1 * s), scale = 1/sqrt(128)
#define C1F (0.08838834764831845f * 1.4426950408889634f)

__device__ __forceinline__ u16 f2bf(float f) {
  unsigned u = __builtin_bit_cast(unsigned, f);
  u += 0x7FFFu + ((u >> 16) & 1u);   // RNE
  return (u16)(u >> 16);
}
__device__ __forceinline__ float bf2f(u16 h) {
  unsigned u = ((unsigned)h) << 16;
  return __builtin_bit_cast(float, u);
}

// async global->LDS, 16B per lane; LDS dest = wave-uniform base + lane*16
__device__ __forceinline__ void async_ld16(const void* g, void* lds) {
  __builtin_amdgcn_global_load_lds(
      (const __attribute__((address_space(1))) unsigned int*)(g),
      (__attribute__((address_space(3))) unsigned int*)(lds), 16, 0, 0);
}

// XOR-swizzled byte offsets (conflict-free frag reads; verified R2: 0 conflicts)
__device__ __forceinline__ int swz16(int row, int chunk) {   // 256B rows
  return row * 256 + ((chunk ^ (row & 15)) << 4);
}
__device__ __forceinline__ int swz8(int row, int chunk) {    // 128B rows
  return row * 128 + ((chunk ^ (row & 7)) << 4);
}

// ---------------------------------------------------------------------------
__global__ __launch_bounds__(256) void zero_f32(float* __restrict__ out,
                                                float* __restrict__ denom) {
  size_t i = (size_t)blockIdx.x * 256 + threadIdx.x;
  float4 z = {0.f, 0.f, 0.f, 0.f};
  if (i < (size_t)MROWS * DDIM / 4) ((float4*)out)[i] = z;
  if (i < (size_t)BSZ * TLEN / 4) ((float4*)denom)[i] = z;
}

// ---------------------------------------------------------------------------
// Wt[w][n][k] = bf16(W_w[k][n])
__global__ __launch_bounds__(256) void prep_w(const float* __restrict__ Wq,
                                              const float* __restrict__ Wk,
                                              const float* __restrict__ Wv,
                                              u16* __restrict__ Wt) {
  int g = blockIdx.x * 256 + threadIdx.x;
  int w = g >> 15;
  int rem = g & 32767;
  int n = rem >> 8;
  int k0 = (rem & 255) * 8;
  const float* W = (w == 0) ? Wq : (w == 1) ? Wk : Wv;
  unsigned pk[4];
  for (int i = 0; i < 4; ++i) {
    u16 lo = f2bf(W[(size_t)(k0 + 2 * i) * DDIM + n]);
    u16 hi = f2bf(W[(size_t)(k0 + 2 * i + 1) * DDIM + n]);
    pk[i] = (unsigned)lo | ((unsigned)hi << 16);
  }
  uint4 v; v.x = pk[0]; v.y = pk[1]; v.z = pk[2]; v.w = pk[3];
  *(uint4*)(Wt + ((size_t)(w * DDIM + n) * EDIM + k0)) = v;
}

// ---------------------------------------------------------------------------
// Fused q,k,v GEMM (unchanged from R2 — passing).
__global__ __launch_bounds__(512, 2) void qkv_gemm(const float* __restrict__ x,
                                                   const u16* __restrict__ Wt,
                                                   u16* __restrict__ qkvb) {
  __shared__ u16 As[128 * 64];
  __shared__ u16 Bs[384 * 64];
  const int tid = threadIdx.x, lane = tid & 63, wave = tid >> 6;
  const int quad = lane >> 4, l15 = lane & 15;
  const int m0 = blockIdx.x * 128;
  const int wm = wave & 1, wn = wave >> 1;

  const f32x4 zero = {0.f, 0.f, 0.f, 0.f};
  f32x4 acc[4][6];
  for (int mi = 0; mi < 4; ++mi)
    for (int ni = 0; ni < 6; ++ni) acc[mi][ni] = zero;

  int arow[4], af4[4];
  for (int i = 0; i < 4; ++i) {
    int c = i * 512 + tid;
    arow[i] = c >> 4;
    af4[i] = c & 15;
  }
  float4 ap[4];
#define LOADA(KT)                                                            \
  for (int i = 0; i < 4; ++i)                                                \
    ap[i] = *(const float4*)(x + (size_t)(m0 + arow[i]) * EDIM + (KT)*64 +   \
                             af4[i] * 4);
  LOADA(0)

  for (int kt = 0; kt < EDIM / 64; ++kt) {
    __syncthreads();
    for (int i = 0; i < 4; ++i) {
      uint2 pk;
      pk.x = (unsigned)f2bf(ap[i].x) | ((unsigned)f2bf(ap[i].y) << 16);
      pk.y = (unsigned)f2bf(ap[i].z) | ((unsigned)f2bf(ap[i].w) << 16);
      *(uint2*)((char*)As + swz8(arow[i], af4[i] >> 1) + (af4[i] & 1) * 8) = pk;
    }
    {
      const int k0 = kt * 64;
      for (int e = 0; e < 6; ++e) {
        int rb = (wave * 6 + e) * 8;
        int r = rb + (lane >> 3);
        int c = (lane & 7) ^ (r & 7);
        async_ld16((const char*)(Wt + (size_t)r * EDIM + k0) + c * 16,
                   (char*)Bs + rb * 128);
      }
    }
    __builtin_amdgcn_s_waitcnt(0);
    __syncthreads();
    if (kt + 1 < EDIM / 64) { LOADA(kt + 1) }
    for (int ks = 0; ks < 2; ++ks) {
      const int ch = ks * 4 + quad;
      bf16x8 afr[4], bfr[6];
      for (int mi = 0; mi < 4; ++mi)
        afr[mi] = *(const bf16x8*)((char*)As + swz8(wm * 64 + mi * 16 + l15, ch));
      for (int ni = 0; ni < 6; ++ni)
        bfr[ni] = *(const bf16x8*)((char*)Bs + swz8(wn * 96 + ni * 16 + l15, ch));
      for (int mi = 0; mi < 4; ++mi)
        for (int ni = 0; ni < 6; ++ni)
          acc[mi][ni] = __builtin_amdgcn_mfma_f32_16x16x32_bf16(afr[mi], bfr[ni], acc[mi][ni], 0, 0, 0);
    }
  }
#undef LOADA
  for (int mi = 0; mi < 4; ++mi)
    for (int ni = 0; ni < 6; ++ni) {
      int n = wn * 96 + ni * 16 + l15;
      u16* ob = qkvb + (size_t)(n >> 7) * MROWS * DDIM;
      int nc = n & 127;
      for (int r = 0; r < 4; ++r) {
        int row = m0 + wm * 64 + mi * 16 + quad * 4 + r;
        ob[(size_t)row * DDIM + nc] = f2bf(acc[mi][ni][r]);
      }
    }
}

// ---------------------------------------------------------------------------
// score_k: block (jt, ic, b) fixes key-tile jt, iterates a chunk of i-tiles.
// Writes E = exp(scale*s)*mask (bf16) into packed tri-tile storage, and
// atomically accumulates column sums into denom.  Steady loop is BARRIER-FREE:
// each wave's Q-stage rows == its A-frag rows == its E rows == its readback
// rows (wave-local LDS); only K (read-only after init) is shared.
__global__ __launch_bounds__(256) void score_k(const u16* __restrict__ qb,
                                               const u16* __restrict__ kb,
                                               char* __restrict__ Epack,
                                               float* __restrict__ denom) {
  __shared__ u16 Kbuf[128 * 128];
  __shared__ u16 Qbuf[128 * 128];
  const int tid = threadIdx.x, lane = tid & 63, wave = tid >> 6;
  const int quad = lane >> 4, l15 = lane & 15;
  const int jt = blockIdx.x, ic = blockIdx.y, b = blockIdx.z;
  const int len = NT - jt;
  const int cl = (len + 3) >> 2;
  if (ic * cl >= len) return;
  const int beg = jt + ic * cl;
  const int end = (beg + cl < NT) ? beg + cl : NT;
  const int j0 = jt * 128;

  {  // stage K tile once (swizzled rows, wave-split)
    const char* gk = (const char*)kb + (size_t)(b * TLEN + j0) * 256;
    for (int e = 0; e < 8; ++e) {
      int rb = (wave * 8 + e) * 4;
      int r = rb + (lane >> 4);
      int c = l15 ^ (r & 15);
      async_ld16(gk + r * 256 + c * 16, (char*)Kbuf + rb * 256);
    }
  }
  __builtin_amdgcn_s_waitcnt(0);
  __syncthreads();

  float csum[8];
  for (int ni = 0; ni < 8; ++ni) csum[ni] = 0.f;
  const f32x4 zero = {0.f, 0.f, 0.f, 0.f};

  for (int it = beg; it < end; ++it) {
    const int i0 = it * 128;
    {  // stage this wave's 32 Q rows (wave-local -> no barrier)
      const char* gq = (const char*)qb + (size_t)(b * TLEN + i0) * 256;
      for (int e = 0; e < 8; ++e) {
        int rb = (wave * 8 + e) * 4;
        int r = rb + (lane >> 4);
        int c = l15 ^ (r & 15);
        async_ld16(gq + r * 256 + c * 16, (char*)Qbuf + rb * 256);
      }
    }
    __builtin_amdgcn_s_waitcnt(0);   // own loads landed (wave-local)

    f32x4 accS[2][8];
    for (int mi = 0; mi < 2; ++mi)
      for (int ni = 0; ni < 8; ++ni) accS[mi][ni] = zero;
    for (int ks = 0; ks < 4; ++ks) {
      const int ch = ks * 4 + quad;
      bf16x8 afr[2], kfr[8];
      for (int mi = 0; mi < 2; ++mi)
        afr[mi] = *(const bf16x8*)((char*)Qbuf + swz16(wave * 32 + mi * 16 + l15, ch));
      for (int ni = 0; ni < 8; ++ni)
        kfr[ni] = *(const bf16x8*)((char*)Kbuf + swz16(ni * 16 + l15, ch));
      for (int mi = 0; mi < 2; ++mi)
        for (int ni = 0; ni < 8; ++ni)
          accS[mi][ni] = __builtin_amdgcn_mfma_f32_16x16x32_bf16(afr[mi], kfr[ni], accS[mi][ni], 0, 0, 0);
    }
    // epilogue: E = exp2(C1*s) (masked), column-sum, write E back into Qbuf
    const bool diag = (it == jt);
    for (int mi = 0; mi < 2; ++mi)
      for (int ni = 0; ni < 8; ++ni)
        for (int r = 0; r < 4; ++r) {
          float e = exp2f(C1F * accS[mi][ni][r]);
          int rrow = wave * 32 + mi * 16 + quad * 4 + r;
          int jl = ni * 16 + l15;
          if (diag && (i0 + rrow) < (j0 + jl)) e = 0.f;
          csum[ni] += e;
          *(u16*)((char*)Qbuf + swz16(rrow, jl >> 3) + (jl & 7) * 2) = f2bf(e);
        }
    // readback own 32 rows -> coalesced global store of the E tile
    char* eslot = Epack + (((size_t)b * NSLOT + (size_t)it * (it + 1) / 2 + jt) << 15);
    for (int e = 0; e < 8; ++e) {
      int row = wave * 32 + e * 4 + (lane >> 4);
      bf16x8 v = *(const bf16x8*)((char*)Qbuf + swz16(row, l15));
      *(bf16x8*)(eslot + row * 256 + l15 * 16) = v;
    }
  }
  // reduce csum: quad-lanes, then cross-wave via LDS, then atomics
  for (int ni = 0; ni < 8; ++ni) {
    csum[ni] += __shfl_xor(csum[ni], 16, 64);
    csum[ni] += __shfl_xor(csum[ni], 32, 64);
  }
  __syncthreads();
  float* red = (float*)Kbuf;
  if (lane < 16)
    for (int ni = 0; ni < 8; ++ni)
      red[wave * 128 + ni * 16 + lane] = csum[ni];
  __syncthreads();
  if (tid < 128)
    atomicAdd(&denom[(size_t)b * TLEN + j0 + tid],
              red[tid] + red[128 + tid] + red[256 + tid] + red[384 + tid]);
}

// ---------------------------------------------------------------------------
// vbT[b][d][t] = vb[b][t][d] / denom[b][t]   (V row-scale folds softmax denom)
__global__ __launch_bounds__(256) void vscale_t(const u16* __restrict__ vb,
                                                const float* __restrict__ denom,
                                                u16* __restrict__ vbT) {
  __shared__ u16 tile[128 * 136];
  const int tid = threadIdx.x;
  const int t0 = blockIdx.x * 128, b = blockIdx.y;
  for (int i = 0; i < 8; ++i) {
    int c = tid + i * 256;
    int tl = c >> 4, ch = c & 15;
    float rd = 1.0f / denom[(size_t)b * TLEN + t0 + tl];
    uint4 v = *(const uint4*)(vb + ((size_t)(b * TLEN + t0 + tl) * DDIM + ch * 8));
    unsigned w[4] = {v.x, v.y, v.z, v.w};
    unsigned o[4];
    for (int j = 0; j < 4; ++j) {
      float lo = bf2f((u16)w[j]) * rd;
      float hi = bf2f((u16)(w[j] >> 16)) * rd;
      o[j] = (unsigned)f2bf(lo) | ((unsigned)f2bf(hi) << 16);
    }
    uint4 ov; ov.x = o[0]; ov.y = o[1]; ov.z = o[2]; ov.w = o[3];
    *(uint4*)(tile + tl * 136 + ch * 8) = ov;
  }
  __syncthreads();
  for (int i = 0; i < 8; ++i) {
    int c = tid + i * 256;
    int d = c >> 4, ch = c & 15;
    unsigned pk[4];
    for (int j = 0; j < 4; ++j) {
      u16 lo = tile[(ch * 8 + 2 * j) * 136 + d];
      u16 hi = tile[(ch * 8 + 2 * j + 1) * 136 + d];
      pk[j] = (unsigned)lo | ((unsigned)hi << 16);
    }
    uint4 v; v.x = pk[0]; v.y = pk[1]; v.z = pk[2]; v.w = pk[3];
    *(uint4*)(vbT + ((size_t)(b * DDIM + d) * TLEN + t0 + ch * 8)) = v;
  }
}

// ---------------------------------------------------------------------------
// pv_k: out[b,i,:] (+)= E[i,:] @ V'  — pure m97-style GEMM, BK=64,
// K-loop over 64-wide j sub-steps chunked by jc (16 sub-steps/chunk).
__global__ __launch_bounds__(256, 3) void pv_k(const char* __restrict__ Epack,
                                               const u16* __restrict__ vbT,
                                               float* __restrict__ out) {
  __shared__ u16 Es[128 * 64];   // [i][j64] swizzled 128B rows
  __shared__ u16 Vs[128 * 64];   // [d][j64] swizzled 128B rows
  const int tid = threadIdx.x, lane = tid & 63, wave = tid >> 6;
  const int quad = lane >> 4, l15 = lane & 15;
  const int it = blockIdx.x, jc = blockIdx.y, b = blockIdx.z;
  const int nsub = 2 * (it + 1);
  const int sBeg = jc * 16;
  if (sBeg >= nsub) return;
  const int sEnd = (sBeg + 16 < nsub) ? sBeg + 16 : nsub;
  const int i0 = it * 128;
  const int wm = wave & 1, wn = wave >> 1;

  const f32x4 zero = {0.f, 0.f, 0.f, 0.f};
  f32x4 accO[4][4];
  for (int mi = 0; mi < 4; ++mi)
    for (int ni = 0; ni < 4; ++ni) accO[mi][ni] = zero;

  const size_t triBase = ((size_t)b * NSLOT + (size_t)it * (it + 1) / 2) << 15;
  const char* vbase = (const char*)vbT + (size_t)b * DDIM * TLEN * 2;

  for (int s = sBeg; s < sEnd; ++s) {
    const int jt = s >> 1, h = s & 1;
    __syncthreads();
    {
      const char* eb = Epack + triBase + ((size_t)jt << 15) + h * 128;
      const char* vb2 = vbase + s * 128;
      for (int e = 0; e < 4; ++e) {
        int rb = (wave * 4 + e) * 8;
        int r = rb + (lane >> 3);
        int c = (lane & 7) ^ (r & 7);
        async_ld16(eb + r * 256 + c * 16, (char*)Es + rb * 128);
        async_ld16(vb2 + (size_t)r * (TLEN * 2) + c * 16, (char*)Vs + rb * 128);
      }
    }
    __builtin_amdgcn_s_waitcnt(0);
    __syncthreads();
    for (int ks = 0; ks < 2; ++ks) {
      const int ch = ks * 4 + quad;
      bf16x8 afr[4], bfr[4];
      for (int mi = 0; mi < 4; ++mi)
        afr[mi] = *(const bf16x8*)((char*)Es + swz8(wm * 64 + mi * 16 + l15, ch));
      for (int ni = 0; ni < 4; ++ni)
        bfr[ni] = *(const bf16x8*)((char*)Vs + swz8(wn * 64 + ni * 16 + l15, ch));
      for (int mi = 0; mi < 4; ++mi)
        for (int ni = 0; ni < 4; ++ni)
          accO[mi][ni] = __builtin_amdgcn_mfma_f32_16x16x32_bf16(afr[mi], bfr[ni], accO[mi][ni], 0, 0, 0);
    }
  }
  const bool excl = (it < 8);   // single contributing block -> plain store
  for (int mi = 0; mi < 4; ++mi)
    for (int ni = 0; ni < 4; ++ni) {
      int d = wn * 64 + ni * 16 + l15;
      for (int r = 0; r < 4; ++r) {
        int row = i0 + wm * 64 + mi * 16 + quad * 4 + r;
        float* dst = &out[((size_t)b * TLEN + row) * DDIM + d];
        if (excl) *dst = accO[mi][ni][r];
        else atomicAdd(dst, accO[mi][ni][r]);
      }
    }
}

// ---------------------------------------------------------------------------
extern "C" void kernel_launch(void* const* d_in, const int* in_sizes, int n_in,
                              void* d_out, int out_size, void* d_ws, size_t ws_size,
                              hipStream_t stream) {
  const float* x  = (const float*)d_in[0];
  const float* Wq = (const float*)d_in[1];
  const float* Wk = (const float*)d_in[2];
  const float* Wv = (const float*)d_in[3];
  float* out = (float*)d_out;

  u16* qb  = (u16*)d_ws;                       // [32768][128] bf16
  u16* kb  = qb  + (size_t)MROWS * DDIM;
  u16* vb  = kb  + (size_t)MROWS * DDIM;
  u16* vbT = vb  + (size_t)MROWS * DDIM;       // [8][128][4096]
  u16* Wt  = vbT + (size_t)MROWS * DDIM;       // [3][128][2048]
  float* denom = (float*)(Wt + (size_t)3 * DDIM * EDIM);  // [8][4096] fp32
  char* Epack = (char*)(denom + (size_t)BSZ * TLEN);      // 8*528*32KB = 138 MB

  hipLaunchKernelGGL(zero_f32, dim3(4096), dim3(256), 0, stream, out, denom);
  hipLaunchKernelGGL(prep_w, dim3(384), dim3(256), 0, stream, Wq, Wk, Wv, Wt);
  hipLaunchKernelGGL(qkv_gemm, dim3(256), dim3(512), 0, stream, x, Wt, qb);
  hipLaunchKernelGGL(score_k, dim3(NT, 4, BSZ), dim3(256), 0, stream, qb, kb, Epack, denom);
  hipLaunchKernelGGL(vscale_t, dim3(NT, BSZ), dim3(256), 0, stream, vb, denom, vbT);
  hipLaunchKernelGGL(pv_k, dim3(NT, 4, BSZ), dim3(256), 0, stream, Epack, vbT, out);
}